// Round 8
// baseline (84.991 us; speedup 1.0000x reference)
//
#include <hip/hip_runtime.h>

#define NB 4
#define LL 8192
#define DD 1024
#define CHUNK 64
#define NT (LL / CHUNK)   // 128 tiles per batch
#define NF (NB * NT)      // 512 blocks
#define EPSV 1e-4f
#define WCUT 1e-7f

typedef float vf4 __attribute__((ext_vector_type(4)));

// Single fused kernel. Per block (b, tile T of 64 positions):
//   Phase 1: full-batch mask scan (L2-resident) -> tile idx/p; one wave computes
//            per-distinct-row weights (suffix products of a=1-p) and cumA;
//            tile aggregate Bvec = sum_r w_r * x_r (independent float4 FMAs).
//   Publish: (A, Bvec) + release flag.  Aggregates are INDEPENDENT across tiles,
//            so the lookback below has O(1) wait depth (unlike an inclusive chain).
//   Phase 2: carry = sum_{j<T} W_j * Bvec_j, W_j = prod_{k>j}^{T-1} A_k, walking
//            j = T-1 down while w > WCUT (bench data: A_tile ~ e^-64 -> 1 term).
//            Skipped-term bound: 127 * O(1) * 1e-7 ~ 4e-5 << 0.107 threshold.
//   Phase 3: output scan seeded with carry; idx/p still in LDS; hid slab re-read
//            is L2/L3-hot (fetched by this same block in phase 1).
__global__ __launch_bounds__(256) void k_all(const float* __restrict__ hid,
                                             const void* __restrict__ mask_raw,
                                             const float* __restrict__ bprob,
                                             float* __restrict__ A,
                                             float* __restrict__ Bvec,
                                             int* __restrict__ flags,
                                             float* __restrict__ out) {
    const int blk = blockIdx.x;            // b*NT + T
    const int b = blk >> 7;                // NT = 128
    const int T = blk & (NT - 1);
    const int l0 = T * CHUNK;
    const int tid = threadIdx.x;           // 256 threads
    const int lane = tid & 63, wv = tid >> 6;

    __shared__ int   s_viol;
    __shared__ int   s_wsum[4];
    __shared__ int   s_base;
    __shared__ int   s_idx[CHUNK];
    __shared__ float s_p[CHUNK];
    __shared__ float s_w[CHUNK];
    __shared__ float s_cumA;
    __shared__ float s_bA;

    // ---- mask dtype detect: int32 little-endian [0/1,0,0,0] vs uint8 (first 1 KB)
    if (tid == 0) s_viol = 0;
    __syncthreads();
    {
        unsigned int w = ((const unsigned int*)mask_raw)[tid];
        if ((w & 0xFFFFFF00u) != 0u || (w & 0xFFu) > 1u) atomicOr(&s_viol, 1);
    }
    __syncthreads();
    const bool is_int = (s_viol == 0);

    // ---- full-batch mask reduction: 256 threads x 32 elems -> exclusive prefix at l0
    const int e0 = b * LL + tid * 32;
    int s = 0;
    if (is_int) {
        const int4* mi = (const int4*)((const int*)mask_raw + e0);
        #pragma unroll
        for (int k = 0; k < 8; ++k) { int4 q = mi[k]; s += q.x + q.y + q.z + q.w; }
    } else {
        const unsigned int* mb = (const unsigned int*)((const unsigned char*)mask_raw + e0);
        #pragma unroll
        for (int k = 0; k < 8; ++k) s += (int)((mb[k] * 0x01010101u) >> 24);
    }
    int v = s;
    #pragma unroll
    for (int off = 1; off < 64; off <<= 1) {
        int u = __shfl_up(v, off, 64);
        if (lane >= off) v += u;
    }
    if (lane == 63) s_wsum[wv] = v;
    __syncthreads();
    int wexcl = 0;
    #pragma unroll
    for (int i = 0; i < 4; ++i) if (i < wv) wexcl += s_wsum[i];
    const int excl = wexcl + (v - s);
    if (tid == T * 2) s_base = excl;       // thread whose 32-elem range starts at l0

    if (tid < CHUNK) {
        const int l = l0 + tid;
        float pv = bprob[((size_t)(b * LL + l)) * 2 + 1];
        pv = fminf(fmaxf(pv, EPSV), 1.0f - EPSV);
        if (l == 0) pv = 1.0f;
        s_p[tid] = pv;
        s_w[tid] = 0.f;
    }
    __syncthreads();

    // ---- wave 0: tile idx scan + suffix-product weights + cumA
    if (wv == 0) {
        int mval;
        if (is_int) mval = ((const int*)mask_raw)[b * LL + l0 + lane];
        else        mval = (int)((const unsigned char*)mask_raw)[b * LL + l0 + lane];
        int c = mval;
        #pragma unroll
        for (int off = 1; off < 64; off <<= 1) {
            int u = __shfl_up(c, off, 64);
            if (lane >= off) c += u;
        }
        const int my_idx = s_base + c - 1;
        s_idx[lane] = my_idx;
        const int r0 = __shfl(my_idx, 0, 64);

        const float a = 1.f - s_p[lane];
        float P = a;                               // inclusive suffix product
        #pragma unroll
        for (int off = 1; off < 64; off <<= 1) {
            float u = __shfl_down(P, off, 64);
            if (lane < 64 - off) P *= u;
        }
        float S = __shfl_down(P, 1, 64);           // exclusive suffix product
        if (lane == 63) S = 1.f;
        atomicAdd(&s_w[my_idx - r0], S * s_p[lane]);
        if (lane == 0) s_cumA = P;
    }
    __syncthreads();

    // ---- Phase 1: weighted gather (independent float4 FMAs over distinct rows)
    const int r0 = s_idx[0];
    const int nrow = s_idx[CHUNK - 1] - r0 + 1;
    const vf4* hbv = (const vf4*)(hid + (size_t)b * LL * DD) + tid;
    const vf4* hb0 = hbv + (size_t)r0 * (DD / 4);
    vf4 acc = {0.f, 0.f, 0.f, 0.f};
    #pragma unroll 4
    for (int r = 0; r < nrow; ++r)
        acc += s_w[r] * hb0[(size_t)r * (DD / 4)];

    // ---- Publish aggregate (round-2-proven release pattern)
    ((vf4*)Bvec)[(size_t)blk * (DD / 4) + tid] = acc;
    if (tid == 0) A[blk] = s_cumA;
    __syncthreads();                                // all stores issued (vmcnt drain)
    if (tid == 0) {
        __threadfence();
        __hip_atomic_store(&flags[blk], 1, __ATOMIC_RELEASE, __HIP_MEMORY_SCOPE_AGENT);
    }

    // ---- Phase 2: O(1)-depth lookback over independent aggregates
    vf4 carry = {0.f, 0.f, 0.f, 0.f};
    float w = 1.f;
    for (int j = T - 1; j >= 0; --j) {
        if (tid == 0) {
            int fl;
            do {
                fl = __hip_atomic_load(&flags[b * NT + j], __ATOMIC_ACQUIRE,
                                       __HIP_MEMORY_SCOPE_AGENT);
            } while (fl == 0);
            s_bA = A[b * NT + j];
        }
        __syncthreads();
        carry += w * ((const vf4*)Bvec)[(size_t)(b * NT + j) * (DD / 4) + tid];
        w *= s_bA;
        __syncthreads();                            // s_bA reused next iteration
        if (w <= WCUT) break;
    }

    // ---- Phase 3: output scan seeded with carry (idx/p in LDS; slab L2/L3-hot)
    vf4 y = carry;
    vf4* ob = (vf4*)(out + ((size_t)b * LL + l0) * DD) + tid;
    #pragma unroll 8
    for (int t = 0; t < CHUNK; ++t) {
        const float p = s_p[t];
        const vf4 x = hbv[(size_t)s_idx[t] * (DD / 4)];
        y = p * x + (1.f - p) * y;
        __builtin_nontemporal_store(y, &ob[(size_t)t * (DD / 4)]);
    }
}

extern "C" void kernel_launch(void* const* d_in, const int* in_sizes, int n_in,
                              void* d_out, int out_size, void* d_ws, size_t ws_size,
                              hipStream_t stream) {
    const float* hid   = (const float*)d_in[0];
    const void*  mask  = d_in[1];
    const float* bprob = (const float*)d_in[2];
    float* out = (float*)d_out;

    char* ws = (char*)d_ws;
    int*   flags = (int*)(ws);                      //   2 KB
    float* A     = (float*)(ws + 4096);             //   2 KB
    float* Bvec  = (float*)(ws + 8192);             //   2 MB

    // flags must start at 0 every call (harness doesn't re-poison between replays)
    hipMemsetAsync(ws, 0, 4096, stream);
    k_all<<<NF, 256, 0, stream>>>(hid, mask, bprob, A, Bvec, flags, out);
}

// Round 9
// 82.336 us; speedup vs baseline: 1.0322x; 1.0322x over previous
//
#include <hip/hip_runtime.h>

#define NB 4
#define LL 8192
#define DD 1024
#define CHUNK 64
#define NT (LL / CHUNK)   // 128 tiles per batch
#define NF (NB * NT)      // 512 blocks
#define EPSV 1e-4f
#define WCUT 1e-7f

// Single fused kernel, 1024 threads/block (thread = one d-column).
//   Phase 1: full-batch mask scan (L2-resident) -> tile idx/p; wave 0 computes
//            per-distinct-row weights (suffix products of a=1-p) and cumA;
//            tile aggregate Bvec = sum_r w_r * x_r (independent scalar FMAs).
//   Publish: (A, Bvec) + agent-scope release flag. Aggregates are INDEPENDENT
//            across tiles -> lookback has O(1) wait depth.
//   Phase 2: carry = sum_{j<T} W_j * Bvec_j walking j=T-1 down while w > WCUT
//            (A_tile ~ e^-64 on this data -> 1 term; adversarial data degrades
//            to the full sum and stays correct; skipped bound ~4e-5 << 0.107).
//   Phase 3: output scan seeded with carry; idx/p in LDS; hid slab L2-hot.
__global__ __launch_bounds__(1024) void k_all(const float* __restrict__ hid,
                                              const void* __restrict__ mask_raw,
                                              const float* __restrict__ bprob,
                                              float* __restrict__ A,
                                              float* __restrict__ Bvec,
                                              int* __restrict__ flags,
                                              float* __restrict__ out) {
    const int blk = blockIdx.x;            // b*NT + T
    const int b = blk >> 7;                // NT = 128
    const int T = blk & (NT - 1);
    const int l0 = T * CHUNK;
    const int tid = threadIdx.x;           // 1024 threads
    const int lane = tid & 63, wv = tid >> 6;   // 16 waves

    __shared__ int   s_viol;
    __shared__ int   s_wsum[16];
    __shared__ int   s_base;
    __shared__ int   s_idx[CHUNK];
    __shared__ float s_p[CHUNK];
    __shared__ float s_w[CHUNK];
    __shared__ float s_cumA;
    __shared__ float s_bA;

    // ---- mask dtype detect: int32 little-endian [0/1,0,0,0] vs uint8 (first 4 KB)
    if (tid == 0) s_viol = 0;
    __syncthreads();
    {
        unsigned int w = ((const unsigned int*)mask_raw)[tid];
        if ((w & 0xFFFFFF00u) != 0u || (w & 0xFFu) > 1u) atomicOr(&s_viol, 1);
    }
    __syncthreads();
    const bool is_int = (s_viol == 0);

    // ---- full-batch mask reduction: 1024 threads x 8 elems -> exclusive prefix at l0
    const int e0 = b * LL + tid * 8;
    int s = 0;
    if (is_int) {
        const int4* mi = (const int4*)((const int*)mask_raw + e0);
        #pragma unroll
        for (int k = 0; k < 2; ++k) { int4 q = mi[k]; s += q.x + q.y + q.z + q.w; }
    } else {
        const unsigned int* mb = (const unsigned int*)((const unsigned char*)mask_raw + e0);
        #pragma unroll
        for (int k = 0; k < 2; ++k) s += (int)((mb[k] * 0x01010101u) >> 24);
    }
    int v = s;
    #pragma unroll
    for (int off = 1; off < 64; off <<= 1) {
        int u = __shfl_up(v, off, 64);
        if (lane >= off) v += u;
    }
    if (lane == 63) s_wsum[wv] = v;
    __syncthreads();
    int wexcl = 0;
    #pragma unroll
    for (int i = 0; i < 16; ++i) if (i < wv) wexcl += s_wsum[i];
    const int excl = wexcl + (v - s);
    if (tid == T * 8) s_base = excl;       // thread whose 8-elem range starts at l0

    if (tid < CHUNK) {
        const int l = l0 + tid;
        float pv = bprob[((size_t)(b * LL + l)) * 2 + 1];
        pv = fminf(fmaxf(pv, EPSV), 1.0f - EPSV);
        if (l == 0) pv = 1.0f;
        s_p[tid] = pv;
        s_w[tid] = 0.f;
    }
    __syncthreads();

    // ---- wave 0: tile idx scan + suffix-product weights + cumA
    if (wv == 0) {
        int mval;
        if (is_int) mval = ((const int*)mask_raw)[b * LL + l0 + lane];
        else        mval = (int)((const unsigned char*)mask_raw)[b * LL + l0 + lane];
        int c = mval;
        #pragma unroll
        for (int off = 1; off < 64; off <<= 1) {
            int u = __shfl_up(c, off, 64);
            if (lane >= off) c += u;
        }
        const int my_idx = s_base + c - 1;
        s_idx[lane] = my_idx;
        const int r0 = __shfl(my_idx, 0, 64);

        const float a = 1.f - s_p[lane];
        float P = a;                               // inclusive suffix product
        #pragma unroll
        for (int off = 1; off < 64; off <<= 1) {
            float u = __shfl_down(P, off, 64);
            if (lane < 64 - off) P *= u;
        }
        float S = __shfl_down(P, 1, 64);           // exclusive suffix product
        if (lane == 63) S = 1.f;
        atomicAdd(&s_w[my_idx - r0], S * s_p[lane]);
        if (lane == 0) s_cumA = P;
    }
    __syncthreads();

    // ---- Phase 1: weighted gather (independent scalar FMAs over distinct rows)
    const int r0 = s_idx[0];
    const int nrow = s_idx[CHUNK - 1] - r0 + 1;
    const float* hb = hid + (size_t)b * LL * DD + tid;
    const float* hb0 = hb + (size_t)r0 * DD;
    float acc = 0.f;
    #pragma unroll 4
    for (int r = 0; r < nrow; ++r)
        acc = fmaf(s_w[r], hb0[(size_t)r * DD], acc);

    // ---- Publish aggregate (proven release pattern)
    Bvec[(size_t)blk * DD + tid] = acc;
    if (tid == 0) A[blk] = s_cumA;
    __syncthreads();                                // vmcnt drained before barrier
    if (tid == 0) {
        __threadfence();
        __hip_atomic_store(&flags[blk], 1, __ATOMIC_RELEASE, __HIP_MEMORY_SCOPE_AGENT);
    }

    // ---- Phase 2: O(1)-depth lookback over independent aggregates
    float carry = 0.f;
    float w = 1.f;
    for (int j = T - 1; j >= 0; --j) {
        if (tid == 0) {
            int fl;
            do {
                fl = __hip_atomic_load(&flags[b * NT + j], __ATOMIC_ACQUIRE,
                                       __HIP_MEMORY_SCOPE_AGENT);
            } while (fl == 0);
            s_bA = A[b * NT + j];
        }
        __syncthreads();
        carry = fmaf(w, Bvec[(size_t)(b * NT + j) * DD + tid], carry);
        w *= s_bA;
        __syncthreads();                            // s_bA reused next iteration
        if (w <= WCUT) break;
    }

    // ---- Phase 3: output scan seeded with carry (idx/p in LDS; slab L2-hot)
    float y = carry;
    float* ob = out + ((size_t)b * LL + l0) * DD + tid;
    #pragma unroll 8
    for (int t = 0; t < CHUNK; ++t) {
        const float p = s_p[t];
        const float x = hb[(size_t)s_idx[t] * DD];
        y = fmaf(p, x, (1.f - p) * y);
        __builtin_nontemporal_store(y, &ob[(size_t)t * DD]);
    }
}

extern "C" void kernel_launch(void* const* d_in, const int* in_sizes, int n_in,
                              void* d_out, int out_size, void* d_ws, size_t ws_size,
                              hipStream_t stream) {
    const float* hid   = (const float*)d_in[0];
    const void*  mask  = d_in[1];
    const float* bprob = (const float*)d_in[2];
    float* out = (float*)d_out;

    char* ws = (char*)d_ws;
    int*   flags = (int*)(ws);                      //   2 KB
    float* A     = (float*)(ws + 4096);             //   2 KB
    float* Bvec  = (float*)(ws + 8192);             //   2 MB

    // flags must start at 0 every call (harness doesn't re-poison between replays)
    hipMemsetAsync(ws, 0, 4096, stream);
    k_all<<<NF, 1024, 0, stream>>>(hid, mask, bprob, A, Bvec, flags, out);
}

// Round 10
// 51.735 us; speedup vs baseline: 1.6428x; 1.5915x over previous
//
#include <hip/hip_runtime.h>

#define NB 4
#define LL 8192
#define DD 1024
#define CHUNK 64
#define NT (LL / CHUNK)   // 128 tiles per batch
#define NF (NB * NT)      // 512 blocks
#define EPSV 1e-4f

// ---------------- K1: fused prep + per-tile weighted-row aggregate ----------------
// 1024 threads/block (thread = one d-column). Each block (b, tile T):
// redundant full-batch mask scan (32 KB, L2-resident) -> tile idx/p; wave 0
// computes per-distinct-row weights (suffix products of a=1-p) and cumA;
// tile aggregate Bvec = sum_r w_r * x_r — independent scalar FMAs over ~32
// contiguous rows (fully coalesced, 32 waves/CU for max read MLP).
__global__ __launch_bounds__(1024) void k_agg(const float* __restrict__ hid,
                                              const void* __restrict__ mask_raw,
                                              const float* __restrict__ bprob,
                                              int* __restrict__ idx_g,
                                              float* __restrict__ p_g,
                                              float* __restrict__ A,
                                              float* __restrict__ Bvec) {
    const int blk = blockIdx.x;            // b*NT + T
    const int b = blk >> 7;                // NT = 128
    const int T = blk & (NT - 1);
    const int l0 = T * CHUNK;
    const int tid = threadIdx.x;           // 1024 threads
    const int lane = tid & 63, wv = tid >> 6;   // 16 waves

    __shared__ int   s_viol;
    __shared__ int   s_wsum[16];
    __shared__ int   s_base;
    __shared__ int   s_idx[CHUNK];
    __shared__ float s_p[CHUNK];
    __shared__ float s_w[CHUNK];
    __shared__ float s_cumA;

    // ---- mask dtype detect: int32 little-endian [0/1,0,0,0] vs uint8 (first 4 KB)
    if (tid == 0) s_viol = 0;
    __syncthreads();
    {
        unsigned int w = ((const unsigned int*)mask_raw)[tid];
        if ((w & 0xFFFFFF00u) != 0u || (w & 0xFFu) > 1u) atomicOr(&s_viol, 1);
    }
    __syncthreads();
    const bool is_int = (s_viol == 0);

    // ---- full-batch mask reduction: 1024 threads x 8 elems -> exclusive prefix at l0
    const int e0 = b * LL + tid * 8;
    int s = 0;
    if (is_int) {
        const int4* mi = (const int4*)((const int*)mask_raw + e0);
        #pragma unroll
        for (int k = 0; k < 2; ++k) { int4 q = mi[k]; s += q.x + q.y + q.z + q.w; }
    } else {
        const unsigned int* mb = (const unsigned int*)((const unsigned char*)mask_raw + e0);
        #pragma unroll
        for (int k = 0; k < 2; ++k) s += (int)((mb[k] * 0x01010101u) >> 24);
    }
    int v = s;
    #pragma unroll
    for (int off = 1; off < 64; off <<= 1) {
        int u = __shfl_up(v, off, 64);
        if (lane >= off) v += u;
    }
    if (lane == 63) s_wsum[wv] = v;
    __syncthreads();
    int wexcl = 0;
    #pragma unroll
    for (int i = 0; i < 16; ++i) if (i < wv) wexcl += s_wsum[i];
    const int excl = wexcl + (v - s);
    if (tid == T * 8) s_base = excl;       // thread whose 8-elem range starts at l0

    if (tid < CHUNK) {
        const int l = l0 + tid;
        float pv = bprob[((size_t)(b * LL + l)) * 2 + 1];
        pv = fminf(fmaxf(pv, EPSV), 1.0f - EPSV);
        if (l == 0) pv = 1.0f;
        s_p[tid] = pv;
        s_w[tid] = 0.f;
    }
    __syncthreads();

    // ---- wave 0: tile idx scan + suffix-product weights + cumA
    if (wv == 0) {
        int mval;
        if (is_int) mval = ((const int*)mask_raw)[b * LL + l0 + lane];
        else        mval = (int)((const unsigned char*)mask_raw)[b * LL + l0 + lane];
        int c = mval;
        #pragma unroll
        for (int off = 1; off < 64; off <<= 1) {
            int u = __shfl_up(c, off, 64);
            if (lane >= off) c += u;
        }
        const int my_idx = s_base + c - 1;
        s_idx[lane] = my_idx;
        const int r0 = __shfl(my_idx, 0, 64);

        const float a = 1.f - s_p[lane];
        float P = a;                               // inclusive suffix product
        #pragma unroll
        for (int off = 1; off < 64; off <<= 1) {
            float u = __shfl_down(P, off, 64);
            if (lane < 64 - off) P *= u;
        }
        float S = __shfl_down(P, 1, 64);           // exclusive suffix product
        if (lane == 63) S = 1.f;
        atomicAdd(&s_w[my_idx - r0], S * s_p[lane]);
        if (lane == 0) s_cumA = P;
    }
    __syncthreads();

    // ---- weighted gather: independent scalar FMAs over nrow contiguous rows
    const int r0 = s_idx[0];
    const int nrow = s_idx[CHUNK - 1] - r0 + 1;
    const float* hb0 = hid + (size_t)b * LL * DD + (size_t)r0 * DD + tid;
    float acc = 0.f;
    #pragma unroll 8
    for (int r = 0; r < nrow; ++r)
        acc = fmaf(s_w[r], hb0[(size_t)r * DD], acc);

    Bvec[(size_t)blk * DD + tid] = acc;
    if (tid == 0) A[blk] = s_cumA;
    if (tid < CHUNK) {
        idx_g[b * LL + l0 + tid] = s_idx[tid];
        p_g[b * LL + l0 + tid]  = s_p[tid];
    }
}

// ---------------- K2: fused carry + final scan (round-7 proven) ---------------------
// Each block (b,T) recomputes its exclusive carry from the tile aggregates:
//   carry = sum_{j<T} W_j * Bvec[j],  W_j = prod_{k=j+1}^{T-1} A_k  (exact, via
// 7-step LDS suffix-product scan). Terms with W_j < 1e-7 skipped — skipped
// contribution <= 128 * O(1) * 1e-7 ~ 6e-5 << 0.107 threshold; adaptive, stays
// correct on adversarial data. Then the tile's output scan seeded with carry.
__global__ __launch_bounds__(1024) void k_fin(const float* __restrict__ hid,
                                              const int* __restrict__ idx,
                                              const float* __restrict__ p_ws,
                                              const float* __restrict__ A,
                                              const float* __restrict__ Bvec,
                                              float* __restrict__ out) {
    const int blk = blockIdx.x;
    const int b = blk >> 7;
    const int T = blk & (NT - 1);
    const int tid = threadIdx.x;
    const int l0 = T * CHUNK;

    __shared__ float s_P[NT];      // s_P[j] = prod_{k=j}^{T-1} A_k (1 for j>=T)
    __shared__ int   s_idx[CHUNK];
    __shared__ float s_p[CHUNK];
    __shared__ int   s_jmin;

    if (tid < CHUNK) {
        s_idx[tid] = idx[b * LL + l0 + tid];
        s_p[tid]  = p_ws[b * LL + l0 + tid];
    }
    if (tid == 128) s_jmin = T;
    if (tid < NT) s_P[tid] = (tid < T) ? A[b * NT + tid] : 1.f;
    __syncthreads();
    #pragma unroll
    for (int off = 1; off < NT; off <<= 1) {
        float self = 1.f, other = 1.f;
        if (tid < NT) { self = s_P[tid]; if (tid + off < NT) other = s_P[tid + off]; }
        __syncthreads();
        if (tid < NT) s_P[tid] = self * other;
        __syncthreads();
    }
    if (tid < T) {
        if (s_P[tid + 1] > 1e-7f) atomicMin(&s_jmin, tid);   // W_tid = s_P[tid+1]
    }
    __syncthreads();

    float carry = 0.f;
    const int jmin = s_jmin;
    for (int j = jmin; j < T; ++j)
        carry = fmaf(s_P[j + 1], Bvec[((size_t)(b * NT + j)) * DD + tid], carry);

    const float* hb = hid + (size_t)b * LL * DD + tid;
    float* ob = out + ((size_t)b * LL + l0) * DD + tid;
    float y = carry;
    #pragma unroll 8
    for (int t = 0; t < CHUNK; ++t) {
        const float p = s_p[t];
        const float x = hb[(size_t)s_idx[t] * DD];
        y = fmaf(p, x, (1.f - p) * y);
        __builtin_nontemporal_store(y, &ob[(size_t)t * DD]);
    }
}

extern "C" void kernel_launch(void* const* d_in, const int* in_sizes, int n_in,
                              void* d_out, int out_size, void* d_ws, size_t ws_size,
                              hipStream_t stream) {
    const float* hid   = (const float*)d_in[0];
    const void*  mask  = d_in[1];
    const float* bprob = (const float*)d_in[2];
    float* out = (float*)d_out;

    char* ws = (char*)d_ws;
    int*   idx   = (int*)(ws);                                   // 128 KB
    float* p_ws  = (float*)(ws + 131072);                        // 128 KB
    float* A     = (float*)(ws + 262144);                        //   2 KB
    float* Bvec  = (float*)(ws + 264192);                        //   2 MB

    k_agg<<<NF, 1024, 0, stream>>>(hid, mask, bprob, idx, p_ws, A, Bvec);
    k_fin<<<NF, 1024, 0, stream>>>(hid, idx, p_ws, A, Bvec, out);
}

// Round 11
// 46.607 us; speedup vs baseline: 1.8235x; 1.1100x over previous
//
#include <hip/hip_runtime.h>

#define NB 4
#define LL 8192
#define DD 1024
#define CHUNK 64
#define NT (LL / CHUNK)   // 128 tiles per batch
#define NF (NB * NT)      // 512 blocks
#define EPSV 1e-4f
#define WCUT 1e-7f

// ONE kernel, no cross-block sync. Block (b, tile T of 64 outputs):
//  1. redundant full-batch mask prefix (32 KB, L2-resident) -> s_excl[] so the
//     boundary-count before ANY position multiple of 8 is available in LDS.
//  2. adaptive warm-up: wave 0 walks back tile-by-tile, multiplying the tile
//     product of a=1-p, until cum < WCUT or position 0 (exact). Truncation
//     error <= WCUT * |carry| ~ 6e-7 << 0.107 threshold; exact when walk hits 0.
//     On this data cum(1 tile) ~ e^-64 -> exactly 1 warm-up tile.
//  3. forward scan from zero seed at l_s: per 64-chunk, wave 0 preps idx/p into
//     a 2-slot LDS ring (1 barrier/chunk), all 1024 threads run the serial
//     EMA over their d-column; the final chunk streams to out (nontemporal).
// XCD-contiguous swizzle: consecutive tiles share warm-up rows in the same L2.
__global__ __launch_bounds__(1024) void k_one(const float* __restrict__ hid,
                                              const void* __restrict__ mask_raw,
                                              const float* __restrict__ bprob,
                                              float* __restrict__ out) {
    const int blk0 = blockIdx.x;
    const int f = (blk0 & 7) * (NF / 8) + (blk0 >> 3);   // 512 = 8 XCDs x 64
    const int b = f >> 7;                 // NT = 128
    const int T = f & (NT - 1);
    const int l0 = T * CHUNK;
    const int tid = threadIdx.x;          // 1024 threads
    const int lane = tid & 63, wv = tid >> 6;

    __shared__ int   s_viol;
    __shared__ int   s_wsum[16];
    __shared__ int   s_excl[1024];        // exclusive boundary-count per 8-elem range
    __shared__ int   s_i[2][CHUNK];
    __shared__ float s_pv[2][CHUNK];
    __shared__ int   s_ls;

    // ---- mask dtype detect: int32 little-endian [0/1,0,0,0] vs uint8 (first 4 KB)
    if (tid == 0) s_viol = 0;
    __syncthreads();
    {
        unsigned int w = ((const unsigned int*)mask_raw)[tid];
        if ((w & 0xFFFFFF00u) != 0u || (w & 0xFFu) > 1u) atomicOr(&s_viol, 1);
    }
    __syncthreads();
    const bool is_int = (s_viol == 0);

    // ---- full-batch mask prefix: 1024 threads x 8 elems
    const int e0 = b * LL + tid * 8;
    int s = 0;
    if (is_int) {
        const int4* mi = (const int4*)((const int*)mask_raw + e0);
        #pragma unroll
        for (int k = 0; k < 2; ++k) { int4 q = mi[k]; s += q.x + q.y + q.z + q.w; }
    } else {
        const unsigned int* mb = (const unsigned int*)((const unsigned char*)mask_raw + e0);
        #pragma unroll
        for (int k = 0; k < 2; ++k) s += (int)((mb[k] * 0x01010101u) >> 24);
    }
    int v = s;
    #pragma unroll
    for (int off = 1; off < 64; off <<= 1) {
        int u = __shfl_up(v, off, 64);
        if (lane >= off) v += u;
    }
    if (lane == 63) s_wsum[wv] = v;
    __syncthreads();
    int wexcl = 0;
    #pragma unroll
    for (int i = 0; i < 16; ++i) if (i < wv) wexcl += s_wsum[i];
    s_excl[tid] = wexcl + (v - s);        // boundaries in [0, 8*tid) of this batch

    // ---- adaptive warm-up walk (wave 0 only; others head to the barrier)
    if (wv == 0) {
        int ls = T;
        float cum = 1.f;
        while (ls > 0 && cum > WCUT) {
            --ls;
            const int l = ls * CHUNK + lane;
            float pv = bprob[((size_t)(b * LL + l)) * 2 + 1];
            pv = fminf(fmaxf(pv, EPSV), 1.0f - EPSV);
            if (l == 0) pv = 1.0f;        // annihilates: exact from 0
            float P = 1.f - pv;
            #pragma unroll
            for (int off = 1; off < 64; off <<= 1)
                P *= __shfl_xor(P, off, 64);      // all-lanes product
            cum *= P;
        }
        if (lane == 0) s_ls = ls;
    }
    __syncthreads();                      // covers s_excl + s_ls visibility
    const int ls = s_ls;

    // ---- forward scan from zero seed at ls*CHUNK; store only chunk T
    const float* hb = hid + (size_t)b * LL * DD + tid;
    float* ob = out + ((size_t)b * LL + l0) * DD + tid;
    float y = 0.f;
    for (int c = ls; c <= T; ++c) {
        const int slot = c & 1;
        if (wv == 0) {                    // JIT prep of chunk c (2-slot ring is safe:
            const int cs = c * CHUNK;     //  prep(c+1) writes the other slot; the
            int mval;                     //  barrier below fences slot reuse at c+2)
            if (is_int) mval = ((const int*)mask_raw)[b * LL + cs + lane];
            else        mval = (int)((const unsigned char*)mask_raw)[b * LL + cs + lane];
            int cc = mval;
            #pragma unroll
            for (int off = 1; off < 64; off <<= 1) {
                int u = __shfl_up(cc, off, 64);
                if (lane >= off) cc += u;
            }
            s_i[slot][lane] = s_excl[c * 8] + cc - 1;
            const int l = cs + lane;
            float pv = bprob[((size_t)(b * LL + l)) * 2 + 1];
            pv = fminf(fmaxf(pv, EPSV), 1.0f - EPSV);
            if (l == 0) pv = 1.0f;
            s_pv[slot][lane] = pv;
        }
        __syncthreads();
        if (c < T) {
            #pragma unroll 8
            for (int t = 0; t < CHUNK; ++t) {
                const float p = s_pv[slot][t];
                const float x = hb[(size_t)s_i[slot][t] * DD];
                y = fmaf(p, x, (1.f - p) * y);
            }
        } else {
            #pragma unroll 8
            for (int t = 0; t < CHUNK; ++t) {
                const float p = s_pv[slot][t];
                const float x = hb[(size_t)s_i[slot][t] * DD];
                y = fmaf(p, x, (1.f - p) * y);
                __builtin_nontemporal_store(y, &ob[(size_t)t * DD]);
            }
        }
    }
}

extern "C" void kernel_launch(void* const* d_in, const int* in_sizes, int n_in,
                              void* d_out, int out_size, void* d_ws, size_t ws_size,
                              hipStream_t stream) {
    const float* hid   = (const float*)d_in[0];
    const void*  mask  = d_in[1];
    const float* bprob = (const float*)d_in[2];
    float* out = (float*)d_out;

    k_one<<<NF, 1024, 0, stream>>>(hid, mask, bprob, out);
}

// Round 12
// 39.145 us; speedup vs baseline: 2.1712x; 1.1906x over previous
//
#include <hip/hip_runtime.h>

#define NB 4
#define LL 8192
#define DD 1024
#define CHUNK 64
#define NT (LL / CHUNK)   // 128 tiles per batch
#define NF (NB * NT)      // 512 blocks
#define EPSV 1e-4f
#define WCUT 1e-7f

// ONE kernel, no cross-block sync. Block (b, tile T of 64 outputs):
//  1. redundant full-batch mask prefix (32 KB, L2-resident) -> s_excl[].
//  2. wave 0 preps own chunk idx/p; wave 1 (concurrently) builds the warm-up:
//     suffix products of a=1-p over chunk T-1, ballot-finds the LATEST l* with
//     S_incl(l*) <= WCUT (exists whenever chunk holds position 0, since p0=1),
//     then folds positions l*..l0-1 into per-row weights w_r (LDS atomicAdd).
//     Truncation error <= WCUT * |y| ~ 5e-7 << 0.107 threshold.
//  3. carry = sum_r w_r * x_r  (~10 INDEPENDENT FMAs over contiguous rows),
//     then the 64-step own-chunk EMA, nontemporal stores.
//  Fallback (no cut in chunk T-1; prob ~1e-9 here, adversarial-safe): wave 1
//  chunk-walks further back, then the round-11 serial ring loop runs — exact.
// XCD-contiguous swizzle keeps neighbor tiles (shared warm-up rows) on one L2.
__global__ __launch_bounds__(1024) void k_one(const float* __restrict__ hid,
                                              const void* __restrict__ mask_raw,
                                              const float* __restrict__ bprob,
                                              float* __restrict__ out) {
    const int blk0 = blockIdx.x;
    const int f = (blk0 & 7) * (NF / 8) + (blk0 >> 3);   // 512 = 8 XCDs x 64
    const int b = f >> 7;                 // NT = 128
    const int T = f & (NT - 1);
    const int l0 = T * CHUNK;
    const int tid = threadIdx.x;          // 1024 threads
    const int lane = tid & 63, wv = tid >> 6;

    __shared__ int   s_viol;
    __shared__ int   s_wsum[16];
    __shared__ int   s_excl[1024];        // boundaries in [0, 8*tid) of this batch
    __shared__ int   s_i[2][CHUNK];
    __shared__ float s_pv[2][CHUNK];
    __shared__ float s_w[CHUNK];
    __shared__ int   s_r0w, s_nrw, s_fb, s_ls;

    if (tid == 0) { s_viol = 0; s_fb = 0; s_nrw = 0; }
    if (tid < CHUNK) s_w[tid] = 0.f;
    __syncthreads();
    // ---- mask dtype detect: int32 little-endian [0/1,0,0,0] vs uint8 (first 4 KB)
    {
        unsigned int w = ((const unsigned int*)mask_raw)[tid];
        if ((w & 0xFFFFFF00u) != 0u || (w & 0xFFu) > 1u) atomicOr(&s_viol, 1);
    }
    __syncthreads();
    const bool is_int = (s_viol == 0);

    // ---- full-batch mask prefix: 1024 threads x 8 elems
    const int e0 = b * LL + tid * 8;
    int s = 0;
    if (is_int) {
        const int4* mi = (const int4*)((const int*)mask_raw + e0);
        #pragma unroll
        for (int k = 0; k < 2; ++k) { int4 q = mi[k]; s += q.x + q.y + q.z + q.w; }
    } else {
        const unsigned int* mb = (const unsigned int*)((const unsigned char*)mask_raw + e0);
        #pragma unroll
        for (int k = 0; k < 2; ++k) s += (int)((mb[k] * 0x01010101u) >> 24);
    }
    int v = s;
    #pragma unroll
    for (int off = 1; off < 64; off <<= 1) {
        int u = __shfl_up(v, off, 64);
        if (lane >= off) v += u;
    }
    if (lane == 63) s_wsum[wv] = v;
    __syncthreads();
    int wexcl = 0;
    #pragma unroll
    for (int i = 0; i < 16; ++i) if (i < wv) wexcl += s_wsum[i];
    s_excl[tid] = wexcl + (v - s);
    __syncthreads();

    // ---- wave 0: own-chunk idx/p prep (into slot 0 for the fast path)
    if (wv == 0) {
        int mval;
        if (is_int) mval = ((const int*)mask_raw)[b * LL + l0 + lane];
        else        mval = (int)((const unsigned char*)mask_raw)[b * LL + l0 + lane];
        int cc = mval;
        #pragma unroll
        for (int off = 1; off < 64; off <<= 1) {
            int u = __shfl_up(cc, off, 64);
            if (lane >= off) cc += u;
        }
        s_i[0][lane] = s_excl[T * 8] + cc - 1;
        const int l = l0 + lane;
        float pv = bprob[((size_t)(b * LL + l)) * 2 + 1];
        pv = fminf(fmaxf(pv, EPSV), 1.0f - EPSV);
        if (l == 0) pv = 1.0f;
        s_pv[0][lane] = pv;
    }
    // ---- wave 1: position-granular warm-up weights from chunk T-1
    if (wv == 1 && T > 0) {
        const int lw = l0 - CHUNK + lane;
        int mval;
        if (is_int) mval = ((const int*)mask_raw)[b * LL + lw];
        else        mval = (int)((const unsigned char*)mask_raw)[b * LL + lw];
        int cc = mval;
        #pragma unroll
        for (int off = 1; off < 64; off <<= 1) {
            int u = __shfl_up(cc, off, 64);
            if (lane >= off) cc += u;
        }
        const int my_idx = s_excl[(T - 1) * 8] + cc - 1;

        float pv = bprob[((size_t)(b * LL + lw)) * 2 + 1];
        pv = fminf(fmaxf(pv, EPSV), 1.0f - EPSV);
        if (lw == 0) pv = 1.0f;
        const float a = 1.f - pv;
        float P = a;                                // inclusive suffix product
        #pragma unroll
        for (int off = 1; off < 64; off <<= 1) {
            float u = __shfl_down(P, off, 64);
            if (lane < 64 - off) P *= u;
        }
        float S = __shfl_down(P, 1, 64);            // exclusive suffix product
        if (lane == 63) S = 1.f;

        const unsigned long long cut = __ballot(P <= WCUT);
        if (cut != 0ull) {
            const int lstar = 63 - __clzll(cut);    // latest position with S_incl<=WCUT
            const int r0w   = __shfl(my_idx, lstar, 64);
            const int rlast = __shfl(my_idx, 63, 64);
            if (lane >= lstar) atomicAdd(&s_w[my_idx - r0w], pv * S);
            if (lane == 0) { s_r0w = r0w; s_nrw = rlast - r0w + 1; }
        } else {
            // rare fallback: keep walking whole chunks back (exact at position 0)
            float cum = __shfl(P, 0, 64);           // full prev-chunk product
            int ls = T - 1;
            while (ls > 0 && cum > WCUT) {
                --ls;
                const int l2 = ls * CHUNK + lane;
                float pv2 = bprob[((size_t)(b * LL + l2)) * 2 + 1];
                pv2 = fminf(fmaxf(pv2, EPSV), 1.0f - EPSV);
                if (l2 == 0) pv2 = 1.0f;
                float P2 = 1.f - pv2;
                #pragma unroll
                for (int off = 1; off < 64; off <<= 1)
                    P2 *= __shfl_xor(P2, off, 64);
                cum *= P2;
            }
            if (lane == 0) { s_fb = 1; s_ls = ls; }
        }
    }
    __syncthreads();

    const float* hb = hid + (size_t)b * LL * DD + tid;
    float* ob = out + ((size_t)b * LL + l0) * DD + tid;

    if (!s_fb) {
        // ---- fast path: parallel weighted warm-up + own-chunk EMA
        float y = 0.f;
        const int nrw = s_nrw;
        if (nrw > 0) {
            const float* hw = hb + (size_t)s_r0w * DD;
            #pragma unroll 4
            for (int r = 0; r < nrw; ++r)
                y = fmaf(s_w[r], hw[(size_t)r * DD], y);
        }
        #pragma unroll 8
        for (int t = 0; t < CHUNK; ++t) {
            const float p = s_pv[0][t];
            const float x = hb[(size_t)s_i[0][t] * DD];
            y = fmaf(p, x, (1.f - p) * y);
            __builtin_nontemporal_store(y, &ob[(size_t)t * DD]);
        }
    } else {
        // ---- exact fallback: round-11 serial ring loop from s_ls
        const int ls = s_ls;
        float y = 0.f;
        for (int c = ls; c <= T; ++c) {
            const int slot = c & 1;
            if (wv == 0) {
                const int cs = c * CHUNK;
                int mval;
                if (is_int) mval = ((const int*)mask_raw)[b * LL + cs + lane];
                else        mval = (int)((const unsigned char*)mask_raw)[b * LL + cs + lane];
                int cc = mval;
                #pragma unroll
                for (int off = 1; off < 64; off <<= 1) {
                    int u = __shfl_up(cc, off, 64);
                    if (lane >= off) cc += u;
                }
                s_i[slot][lane] = s_excl[c * 8] + cc - 1;
                const int l = cs + lane;
                float pv = bprob[((size_t)(b * LL + l)) * 2 + 1];
                pv = fminf(fmaxf(pv, EPSV), 1.0f - EPSV);
                if (l == 0) pv = 1.0f;
                s_pv[slot][lane] = pv;
            }
            __syncthreads();
            if (c < T) {
                #pragma unroll 8
                for (int t = 0; t < CHUNK; ++t) {
                    const float p = s_pv[slot][t];
                    const float x = hb[(size_t)s_i[slot][t] * DD];
                    y = fmaf(p, x, (1.f - p) * y);
                }
            } else {
                #pragma unroll 8
                for (int t = 0; t < CHUNK; ++t) {
                    const float p = s_pv[slot][t];
                    const float x = hb[(size_t)s_i[slot][t] * DD];
                    y = fmaf(p, x, (1.f - p) * y);
                    __builtin_nontemporal_store(y, &ob[(size_t)t * DD]);
                }
            }
        }
    }
}

extern "C" void kernel_launch(void* const* d_in, const int* in_sizes, int n_in,
                              void* d_out, int out_size, void* d_ws, size_t ws_size,
                              hipStream_t stream) {
    const float* hid   = (const float*)d_in[0];
    const void*  mask  = d_in[1];
    const float* bprob = (const float*)d_in[2];
    float* out = (float*)d_out;

    k_one<<<NF, 1024, 0, stream>>>(hid, mask, bprob, out);
}